// Round 8
// baseline (491.878 us; speedup 1.0000x reference)
//
#include <hip/hip_runtime.h>

#define N_NODES 100000
#define N_EDGES 3200000
#define DIN 128
#define HID 64
#define N_GRAPH 256

#define BSHIFT 8
#define NB 391              // ceil(N_NODES / 256)
#define CHUNK 4096          // edges per k_place block
#define EPT (CHUNK / 256)   // edges per thread in k_place

typedef __attribute__((ext_vector_type(8))) short bf16x8;
typedef __attribute__((ext_vector_type(4))) float f32x4;

__device__ inline short bf16_rne(float x) {
  union { float f; unsigned u; } a; a.f = x;
  unsigned r = (a.u + 0x7fffu + ((a.u >> 16) & 1u)) >> 16;
  return (short)r;
}
__device__ inline float bf16_to_f(unsigned short h) {
  union { unsigned u; float f; } b; b.u = ((unsigned)h) << 16;
  return b.f;
}

// ---------------- pass 1: coarse bucket histogram ----------------
__global__ __launch_bounds__(256) void k_hist(const int* __restrict__ col,
                                              int* __restrict__ bhist) {
  __shared__ int lh[NB];
  for (int i = threadIdx.x; i < NB; i += 256) lh[i] = 0;
  __syncthreads();
  int stride = gridDim.x * 256;
  for (int e = blockIdx.x * 256 + threadIdx.x; e < N_EDGES; e += stride)
    atomicAdd(&lh[col[e] >> BSHIFT], 1);
  __syncthreads();
  for (int i = threadIdx.x; i < NB; i += 256)
    if (lh[i]) atomicAdd(&bhist[i], lh[i]);
}

// ---------------- tiny scan of bucket counts -> base & cursor ----------------
__global__ __launch_bounds__(256) void k_scanB(const int* __restrict__ bhist,
                                               int* __restrict__ bbase,
                                               int* __restrict__ bcur) {
  __shared__ int h[NB];
  __shared__ int o[NB + 1];
  for (int i = threadIdx.x; i < NB; i += 256) h[i] = bhist[i];
  __syncthreads();
  if (threadIdx.x == 0) {
    int s = 0;
    for (int i = 0; i < NB; ++i) { o[i] = s; s += h[i]; }
    o[NB] = s;
  }
  __syncthreads();
  for (int i = threadIdx.x; i <= NB; i += 256) bbase[i] = o[i];
  for (int i = threadIdx.x; i < NB; i += 256) bcur[i] = o[i];
}

// ------- pass 2: place packed (src<<8 | dst&255) grouped by bucket -------
__global__ __launch_bounds__(256) void k_place(const int* __restrict__ ei,
                                               int* __restrict__ bcur,
                                               int* __restrict__ pairs) {
  __shared__ int lh[NB], lbase[NB], lcur[NB];
  for (int i = threadIdx.x; i < NB; i += 256) { lh[i] = 0; lcur[i] = 0; }
  __syncthreads();
  int base = blockIdx.x * CHUNK;
  int srcs[EPT], dsts[EPT];
#pragma unroll
  for (int k = 0; k < EPT; ++k) {
    int e = base + k * 256 + threadIdx.x;
    if (e < N_EDGES) {
      srcs[k] = ei[e];
      dsts[k] = ei[N_EDGES + e];
      atomicAdd(&lh[dsts[k] >> BSHIFT], 1);
    } else {
      dsts[k] = -1;
    }
  }
  __syncthreads();
  for (int i = threadIdx.x; i < NB; i += 256)
    lbase[i] = lh[i] ? atomicAdd(&bcur[i], lh[i]) : 0;
  __syncthreads();
#pragma unroll
  for (int k = 0; k < EPT; ++k) {
    if (dsts[k] >= 0) {
      int b = dsts[k] >> BSHIFT;
      int l = atomicAdd(&lcur[b], 1);
      pairs[lbase[b] + l] = (srcs[k] << 8) | (dsts[k] & 255);
    }
  }
}

// ---------------- pass 3: per-bucket CSR build + degree/dinv ----------------
__global__ __launch_bounds__(256) void k_build(const int* __restrict__ pairs,
                                               const int* __restrict__ bbase,
                                               int* __restrict__ rowptr,
                                               int* __restrict__ adj,
                                               float* __restrict__ dinv) {
  int b = blockIdx.x;
  int t = threadIdx.x;
  __shared__ int lh[256], lsc[256], lcur[256];
  __shared__ int wsum[4];
  lh[t] = 0;
  lcur[t] = 0;
  __syncthreads();
  int s0 = bbase[b], s1 = bbase[b + 1];
  for (int j = s0 + t; j < s1; j += 256) {
    int p = pairs[j];
    atomicAdd(&lh[p & 255], 1);
  }
  __syncthreads();
  int v = lh[t];
  int lane = t & 63, wv = t >> 6;
  int s = v;
#pragma unroll
  for (int off = 1; off < 64; off <<= 1) {
    int u = __shfl_up(s, off);
    if (lane >= off) s += u;
  }
  if (lane == 63) wsum[wv] = s;
  __syncthreads();
  int pre = 0;
  for (int w = 0; w < wv; ++w) pre += wsum[w];
  lsc[t] = pre + s - v;  // exclusive prefix
  __syncthreads();
  int node = (b << BSHIFT) + t;
  if (node < N_NODES) {
    rowptr[node] = s0 + lsc[t];
    dinv[node] = rsqrtf((float)(v + 1));  // +1 self loop
  }
  if (b == NB - 1 && t == 0) rowptr[N_NODES] = N_EDGES;
  __syncthreads();
  for (int j = s0 + t; j < s1; j += 256) {
    int p = pairs[j];
    int d = p & 255;
    int l = atomicAdd(&lcur[d], 1);
    adj[s0 + lsc[d] + l] = p >> 8;
  }
}

// -------- MFMA GEMM (split-bf16 f32 emulation): Hs = bf16((X @ W) * dinv[row]) --------
// block = 256 thr = 4 waves; wave w owns rows [blk*64 + w*16, +16); K in {128,64}
template <int K>
__global__ __launch_bounds__(256) void k_gemm_mfma(const float* __restrict__ X,
                                                   const float* __restrict__ W,
                                                   const float* __restrict__ dinv,
                                                   unsigned short* __restrict__ Hs) {
  __shared__ short WTh[64 * K];  // W^T hi, [n][k] bf16, XOR-swizzled
  __shared__ short WTl[64 * K];  // W^T lo
  const int t = threadIdx.x;
  constexpr int KC = K / 8;
  if (t < 16 * KC) {
    int ng = t / KC;            // n-group of 4
    int k0 = (t % KC) * 8;
    float w[8][4];
#pragma unroll
    for (int j = 0; j < 8; ++j)
      *(f32x4*)&w[j][0] = *(const f32x4*)&W[(k0 + j) * HID + ng * 4];
#pragma unroll
    for (int c = 0; c < 4; ++c) {
      int n = ng * 4 + c;
      union { short s[8]; int4 i4; } uh, ul;
#pragma unroll
      for (int j = 0; j < 8; ++j) {
        short hi = bf16_rne(w[j][c]);
        uh.s[j] = hi;
        ul.s[j] = bf16_rne(w[j][c] - bf16_to_f((unsigned short)hi));
      }
      int byte = (n * K + k0) * 2;
      byte ^= ((n & 7) << 4);
      *(int4*)((char*)WTh + byte) = uh.i4;
      *(int4*)((char*)WTl + byte) = ul.i4;
    }
  }
  __syncthreads();
  const int wave = t >> 6, lane = t & 63;
  const int row0 = blockIdx.x * 64 + wave * 16;
  if (row0 >= N_NODES) return;
  const int mrow = lane & 15;  // A-row within tile / D-col within tile
  const int kq = lane >> 4;    // k-quarter
  f32x4 acc[4] = {f32x4{0,0,0,0}, f32x4{0,0,0,0}, f32x4{0,0,0,0}, f32x4{0,0,0,0}};
#pragma unroll
  for (int kk = 0; kk < K; kk += 32) {
    int k0 = kk + kq * 8;
    const float* xp = &X[(long)(row0 + mrow) * K + k0];
    f32x4 v0 = *(const f32x4*)xp;
    f32x4 v1 = *(const f32x4*)(xp + 4);
    union { short s[8]; bf16x8 v; } ah, al;
#pragma unroll
    for (int j = 0; j < 4; ++j) {
      short h0 = bf16_rne(v0[j]);
      ah.s[j] = h0;
      al.s[j] = bf16_rne(v0[j] - bf16_to_f((unsigned short)h0));
      short h1 = bf16_rne(v1[j]);
      ah.s[4 + j] = h1;
      al.s[4 + j] = bf16_rne(v1[j] - bf16_to_f((unsigned short)h1));
    }
#pragma unroll
    for (int nt = 0; nt < 4; ++nt) {
      int n = nt * 16 + mrow;
      int byte = (n * K + k0) * 2;
      byte ^= ((n & 7) << 4);
      bf16x8 bh = *(bf16x8*)((char*)WTh + byte);
      bf16x8 bl = *(bf16x8*)((char*)WTl + byte);
      acc[nt] = __builtin_amdgcn_mfma_f32_16x16x32_bf16(ah.v, bh, acc[nt], 0, 0, 0);
      acc[nt] = __builtin_amdgcn_mfma_f32_16x16x32_bf16(ah.v, bl, acc[nt], 0, 0, 0);
      acc[nt] = __builtin_amdgcn_mfma_f32_16x16x32_bf16(al.v, bh, acc[nt], 0, 0, 0);
    }
  }
  // D: col = nt*16 + (lane&15), row = kq*4 + r  [measured m89 layout]
#pragma unroll
  for (int r = 0; r < 4; ++r) {
    int row = row0 + kq * 4 + r;
    float dv = dinv[row];
#pragma unroll
    for (int nt = 0; nt < 4; ++nt)
      Hs[((long)row << 6) + nt * 16 + mrow] = (unsigned short)bf16_rne(acc[nt][r] * dv);
  }
}

// ------- gather (packed, 2 edges/iter): out[n] = act(dinv[n]*(hs[n]+sum hs[src]) + b) -------
// hs32: node row = 32 uints (64 bf16). Row N_NODES is an all-zero sentinel.
template <bool RELU>
__global__ __launch_bounds__(256) void k_gather(const unsigned* __restrict__ hs32,
                                                const int* __restrict__ rowptr,
                                                const int* __restrict__ adj,
                                                const float* __restrict__ dinv,
                                                const float* __restrict__ b,
                                                float* __restrict__ outb) {
  int n = blockIdx.x * 4 + (threadIdx.x >> 6);
  if (n >= N_NODES) return;
  int lane = threadIdx.x & 63;
  int half = lane >> 5;   // which edge of each pair this half-wave handles
  int hl = lane & 31;     // uint index within the 64-feat row
  int s0 = rowptr[n], e0 = rowptr[n + 1];
  float acc0 = 0.f, acc1 = 0.f;
  for (int j = s0; j < e0; j += 64) {
    int cnt = min(64, e0 - j);
    // invalid slots -> sentinel zero row: no tail guard needed in inner loop
    int myadj = (lane < cnt) ? adj[j + lane] : N_NODES;
    int npair = (cnt + 1) >> 1;
    for (int i = 0; i < npair; ++i) {
      int a = __shfl(myadj, 2 * i + half);
      unsigned u = hs32[((unsigned)a << 5) + hl];
      union { unsigned u; float f; } lo, hi;
      lo.u = u << 16;
      hi.u = u & 0xffff0000u;
      acc0 += lo.f;
      acc1 += hi.f;
    }
  }
  // combine the two half-wave partial sums
  acc0 += __shfl_xor(acc0, 32);
  acc1 += __shfl_xor(acc1, 32);
  // self loop
  unsigned us = hs32[((unsigned)n << 5) + hl];
  union { unsigned u; float f; } slo, shi;
  slo.u = us << 16;
  shi.u = us & 0xffff0000u;
  acc0 += slo.f;
  acc1 += shi.f;
  float dv = dinv[n];
  float2 bb = *(const float2*)&b[2 * hl];
  float v0 = dv * acc0 + bb.x;
  float v1 = dv * acc1 + bb.y;
  if (RELU) { v0 = fmaxf(v0, 0.f); v1 = fmaxf(v1, 0.f); }
  if (half == 0)
    *(float2*)&outb[((long)n << 6) + 2 * hl] = make_float2(v0, v1);
}

// ---------------- pooling: mean + max per sorted-batch segment ----------------
__global__ __launch_bounds__(256) void k_pool(const float* __restrict__ Hf,
                                              const int* __restrict__ batch,
                                              float* __restrict__ pooled) {
  int g = blockIdx.x;
  int start, end;
  {
    int lo = 0, hi = N_NODES;
    while (lo < hi) { int mid = (lo + hi) >> 1; if (batch[mid] < g) lo = mid + 1; else hi = mid; }
    start = lo;
    lo = start; hi = N_NODES;
    while (lo < hi) { int mid = (lo + hi) >> 1; if (batch[mid] < g + 1) lo = mid + 1; else hi = mid; }
    end = lo;
  }
  int lane = threadIdx.x & 63, wave = threadIdx.x >> 6;
  float sum = 0.f, mx = -INFINITY;
  for (int n = start + wave; n < end; n += 4) {
    float v = Hf[((long)n << 6) + lane];
    sum += v;
    mx = fmaxf(mx, v);
  }
  __shared__ float ssum[4][HID];
  __shared__ float smax[4][HID];
  ssum[wave][lane] = sum;
  smax[wave][lane] = mx;
  __syncthreads();
  if (wave == 0) {
    sum = ssum[0][lane] + ssum[1][lane] + ssum[2][lane] + ssum[3][lane];
    mx = fmaxf(fmaxf(smax[0][lane], smax[1][lane]), fmaxf(smax[2][lane], smax[3][lane]));
    int cnt = end - start;
    float mean;
    if (cnt == 0) { mean = 0.f; mx = 0.f; }
    else mean = sum / (float)cnt;
    pooled[g * 2 * HID + lane] = mean;
    pooled[g * 2 * HID + HID + lane] = mx;
  }
}

// ---------------- MLP head ----------------
__global__ __launch_bounds__(64) void k_head(const float* __restrict__ pooled,
                                             const float* __restrict__ fcW1,
                                             const float* __restrict__ fcb1,
                                             const float* __restrict__ fcW2,
                                             const float* __restrict__ fcb2,
                                             float* __restrict__ out) {
  int g = blockIdx.x;
  int lane = threadIdx.x;  // 64
  __shared__ float p[2 * HID];
  p[lane] = pooled[g * 2 * HID + lane];
  p[HID + lane] = pooled[g * 2 * HID + HID + lane];
  __syncthreads();
  float acc = fcb1[lane];
#pragma unroll
  for (int k = 0; k < 2 * HID; ++k) acc += p[k] * fcW1[k * HID + lane];
  acc = fmaxf(acc, 0.f);
  float contrib = acc * fcW2[lane];
#pragma unroll
  for (int off = 32; off > 0; off >>= 1) contrib += __shfl_down(contrib, off);
  if (lane == 0) out[g] = contrib + fcb2[0];
}

extern "C" void kernel_launch(void* const* d_in, const int* in_sizes, int n_in,
                              void* d_out, int out_size, void* d_ws, size_t ws_size,
                              hipStream_t stream) {
  const float* x    = (const float*)d_in[0];
  const int*   ei   = (const int*)d_in[1];
  const int*   bat  = (const int*)d_in[2];
  const float* W1   = (const float*)d_in[3];
  const float* b1   = (const float*)d_in[4];
  const float* W2   = (const float*)d_in[5];
  const float* b2   = (const float*)d_in[6];
  const float* fcW1 = (const float*)d_in[7];
  const float* fcb1 = (const float*)d_in[8];
  const float* fcW2 = (const float*)d_in[9];
  const float* fcb2 = (const float*)d_in[10];
  float* out = (float*)d_out;

  char* ws = (char*)d_ws;
  size_t off = 0;
  auto align = [&]() { off = (off + 127) & ~127ul; };
  int*   bhist  = (int*)(ws + off);   off += NB * 4;            align();
  int*   bbase  = (int*)(ws + off);   off += (NB + 1) * 4;      align();
  int*   bcur   = (int*)(ws + off);   off += NB * 4;            align();
  int*   rowptr = (int*)(ws + off);   off += (N_NODES + 1) * 4; align();
  float* dinv   = (float*)(ws + off); off += N_NODES * 4;       align();
  float* pooled = (float*)(ws + off); off += N_GRAPH * 2 * HID * 4; align();
  int*   adj    = (int*)(ws + off);   off += (size_t)N_EDGES * 4;   align();
  unsigned short* hs = (unsigned short*)(ws + off);
  off += ((size_t)N_NODES + 1) * HID * 2;  // +1 zero sentinel row
  align();
  float* ob     = (float*)(ws + off); off += (size_t)N_NODES * HID * 4;
  int*   pairs  = (int*)ob;  // alias: pairs dead before first write of ob

  // zero the sentinel row (ws is poisoned 0xAA before every call)
  hipMemsetAsync(hs + (size_t)N_NODES * HID, 0, HID * 2, stream);

  // ---- CSR build (shared by both layers) + dinv ----
  hipMemsetAsync(bhist, 0, NB * sizeof(int), stream);
  k_hist<<<400, 256, 0, stream>>>(ei + N_EDGES, bhist);
  k_scanB<<<1, 256, 0, stream>>>(bhist, bbase, bcur);
  k_place<<<(N_EDGES + CHUNK - 1) / CHUNK, 256, 0, stream>>>(ei, bcur, pairs);
  k_build<<<NB, 256, 0, stream>>>(pairs, bbase, rowptr, adj, dinv);

  // ---- layer 1: hs1 = bf16((x@W1)*dinv) ; ob = relu(dinv*(hs1 + gather) + b1) ----
  k_gemm_mfma<DIN><<<(N_NODES + 63) / 64, 256, 0, stream>>>(x, W1, dinv, hs);
  k_gather<true><<<(N_NODES + 3) / 4, 256, 0, stream>>>((const unsigned*)hs, rowptr, adj, dinv, b1, ob);

  // ---- layer 2: hs2 = bf16((ob@W2)*dinv) ; ob = dinv*(hs2 + gather) + b2 ----
  k_gemm_mfma<HID><<<(N_NODES + 63) / 64, 256, 0, stream>>>(ob, W2, dinv, hs);
  k_gather<false><<<(N_NODES + 3) / 4, 256, 0, stream>>>((const unsigned*)hs, rowptr, adj, dinv, b2, ob);

  // ---- pooling + head ----
  k_pool<<<N_GRAPH, 256, 0, stream>>>(ob, bat, pooled);
  k_head<<<N_GRAPH, 64, 0, stream>>>(pooled, fcW1, fcb1, fcW2, fcb2, out);
}

// Round 9
// 393.467 us; speedup vs baseline: 1.2501x; 1.2501x over previous
//
#include <hip/hip_runtime.h>

#define N_NODES 100000
#define N_EDGES 3200000
#define DIN 128
#define HID 64
#define N_GRAPH 256

#define BSHIFT 8
#define NB 391              // ceil(N_NODES / 256)
#define CHUNK 4096          // edges per k_place block
#define EPT (CHUNK / 256)   // edges per thread in k_place

typedef __attribute__((ext_vector_type(8))) short bf16x8;
typedef __attribute__((ext_vector_type(4))) float f32x4;

__device__ inline short bf16_rne(float x) {
  union { float f; unsigned u; } a; a.f = x;
  unsigned r = (a.u + 0x7fffu + ((a.u >> 16) & 1u)) >> 16;
  return (short)r;
}
__device__ inline float bf16_to_f(unsigned short h) {
  union { unsigned u; float f; } b; b.u = ((unsigned)h) << 16;
  return b.f;
}

// ---------------- pass 1: coarse bucket histogram ----------------
__global__ __launch_bounds__(256) void k_hist(const int* __restrict__ col,
                                              int* __restrict__ bhist) {
  __shared__ int lh[NB];
  for (int i = threadIdx.x; i < NB; i += 256) lh[i] = 0;
  __syncthreads();
  int stride = gridDim.x * 256;
  for (int e = blockIdx.x * 256 + threadIdx.x; e < N_EDGES; e += stride)
    atomicAdd(&lh[col[e] >> BSHIFT], 1);
  __syncthreads();
  for (int i = threadIdx.x; i < NB; i += 256)
    if (lh[i]) atomicAdd(&bhist[i], lh[i]);
}

// ---------------- tiny scan of bucket counts -> base & cursor ----------------
__global__ __launch_bounds__(256) void k_scanB(const int* __restrict__ bhist,
                                               int* __restrict__ bbase,
                                               int* __restrict__ bcur) {
  __shared__ int h[NB];
  __shared__ int o[NB + 1];
  for (int i = threadIdx.x; i < NB; i += 256) h[i] = bhist[i];
  __syncthreads();
  if (threadIdx.x == 0) {
    int s = 0;
    for (int i = 0; i < NB; ++i) { o[i] = s; s += h[i]; }
    o[NB] = s;
  }
  __syncthreads();
  for (int i = threadIdx.x; i <= NB; i += 256) bbase[i] = o[i];
  for (int i = threadIdx.x; i < NB; i += 256) bcur[i] = o[i];
}

// ------- pass 2: place packed (src<<8 | dst&255) grouped by bucket -------
__global__ __launch_bounds__(256) void k_place(const int* __restrict__ ei,
                                               int* __restrict__ bcur,
                                               int* __restrict__ pairs) {
  __shared__ int lh[NB], lbase[NB], lcur[NB];
  for (int i = threadIdx.x; i < NB; i += 256) { lh[i] = 0; lcur[i] = 0; }
  __syncthreads();
  int base = blockIdx.x * CHUNK;
  int srcs[EPT], dsts[EPT];
#pragma unroll
  for (int k = 0; k < EPT; ++k) {
    int e = base + k * 256 + threadIdx.x;
    if (e < N_EDGES) {
      srcs[k] = ei[e];
      dsts[k] = ei[N_EDGES + e];
      atomicAdd(&lh[dsts[k] >> BSHIFT], 1);
    } else {
      dsts[k] = -1;
    }
  }
  __syncthreads();
  for (int i = threadIdx.x; i < NB; i += 256)
    lbase[i] = lh[i] ? atomicAdd(&bcur[i], lh[i]) : 0;
  __syncthreads();
#pragma unroll
  for (int k = 0; k < EPT; ++k) {
    if (dsts[k] >= 0) {
      int b = dsts[k] >> BSHIFT;
      int l = atomicAdd(&lcur[b], 1);
      pairs[lbase[b] + l] = (srcs[k] << 8) | (dsts[k] & 255);
    }
  }
}

// ---------------- pass 3: per-bucket CSR build + degree/dinv ----------------
__global__ __launch_bounds__(256) void k_build(const int* __restrict__ pairs,
                                               const int* __restrict__ bbase,
                                               int* __restrict__ rowptr,
                                               int* __restrict__ adj,
                                               float* __restrict__ dinv) {
  int b = blockIdx.x;
  int t = threadIdx.x;
  __shared__ int lh[256], lsc[256], lcur[256];
  __shared__ int wsum[4];
  lh[t] = 0;
  lcur[t] = 0;
  __syncthreads();
  int s0 = bbase[b], s1 = bbase[b + 1];
  for (int j = s0 + t; j < s1; j += 256) {
    int p = pairs[j];
    atomicAdd(&lh[p & 255], 1);
  }
  __syncthreads();
  int v = lh[t];
  int lane = t & 63, wv = t >> 6;
  int s = v;
#pragma unroll
  for (int off = 1; off < 64; off <<= 1) {
    int u = __shfl_up(s, off);
    if (lane >= off) s += u;
  }
  if (lane == 63) wsum[wv] = s;
  __syncthreads();
  int pre = 0;
  for (int w = 0; w < wv; ++w) pre += wsum[w];
  lsc[t] = pre + s - v;  // exclusive prefix
  __syncthreads();
  int node = (b << BSHIFT) + t;
  if (node < N_NODES) {
    rowptr[node] = s0 + lsc[t];
    dinv[node] = rsqrtf((float)(v + 1));  // +1 self loop
  }
  if (b == NB - 1 && t == 0) rowptr[N_NODES] = N_EDGES;
  __syncthreads();
  for (int j = s0 + t; j < s1; j += 256) {
    int p = pairs[j];
    int d = p & 255;
    int l = atomicAdd(&lcur[d], 1);
    adj[s0 + lsc[d] + l] = p >> 8;
  }
}

// -------- MFMA GEMM (split-bf16 f32 emulation): Hs = bf16((X @ W) * dinv[row]) --------
// block = 256 thr = 4 waves; wave w owns rows [blk*64 + w*16, +16); K in {128,64}
template <int K>
__global__ __launch_bounds__(256) void k_gemm_mfma(const float* __restrict__ X,
                                                   const float* __restrict__ W,
                                                   const float* __restrict__ dinv,
                                                   unsigned short* __restrict__ Hs) {
  __shared__ short WTh[64 * K];  // W^T hi, [n][k] bf16, XOR-swizzled
  __shared__ short WTl[64 * K];  // W^T lo
  const int t = threadIdx.x;
  constexpr int KC = K / 8;
  if (t < 16 * KC) {
    int ng = t / KC;            // n-group of 4
    int k0 = (t % KC) * 8;
    float w[8][4];
#pragma unroll
    for (int j = 0; j < 8; ++j)
      *(f32x4*)&w[j][0] = *(const f32x4*)&W[(k0 + j) * HID + ng * 4];
#pragma unroll
    for (int c = 0; c < 4; ++c) {
      int n = ng * 4 + c;
      union { short s[8]; int4 i4; } uh, ul;
#pragma unroll
      for (int j = 0; j < 8; ++j) {
        short hi = bf16_rne(w[j][c]);
        uh.s[j] = hi;
        ul.s[j] = bf16_rne(w[j][c] - bf16_to_f((unsigned short)hi));
      }
      int byte = (n * K + k0) * 2;
      byte ^= ((n & 7) << 4);
      *(int4*)((char*)WTh + byte) = uh.i4;
      *(int4*)((char*)WTl + byte) = ul.i4;
    }
  }
  __syncthreads();
  const int wave = t >> 6, lane = t & 63;
  const int row0 = blockIdx.x * 64 + wave * 16;
  if (row0 >= N_NODES) return;
  const int mrow = lane & 15;  // A-row within tile / D-col within tile
  const int kq = lane >> 4;    // k-quarter
  f32x4 acc[4] = {f32x4{0,0,0,0}, f32x4{0,0,0,0}, f32x4{0,0,0,0}, f32x4{0,0,0,0}};
#pragma unroll
  for (int kk = 0; kk < K; kk += 32) {
    int k0 = kk + kq * 8;
    const float* xp = &X[(long)(row0 + mrow) * K + k0];
    f32x4 v0 = *(const f32x4*)xp;
    f32x4 v1 = *(const f32x4*)(xp + 4);
    union { short s[8]; bf16x8 v; } ah, al;
#pragma unroll
    for (int j = 0; j < 4; ++j) {
      short h0 = bf16_rne(v0[j]);
      ah.s[j] = h0;
      al.s[j] = bf16_rne(v0[j] - bf16_to_f((unsigned short)h0));
      short h1 = bf16_rne(v1[j]);
      ah.s[4 + j] = h1;
      al.s[4 + j] = bf16_rne(v1[j] - bf16_to_f((unsigned short)h1));
    }
#pragma unroll
    for (int nt = 0; nt < 4; ++nt) {
      int n = nt * 16 + mrow;
      int byte = (n * K + k0) * 2;
      byte ^= ((n & 7) << 4);
      bf16x8 bh = *(bf16x8*)((char*)WTh + byte);
      bf16x8 bl = *(bf16x8*)((char*)WTl + byte);
      acc[nt] = __builtin_amdgcn_mfma_f32_16x16x32_bf16(ah.v, bh, acc[nt], 0, 0, 0);
      acc[nt] = __builtin_amdgcn_mfma_f32_16x16x32_bf16(ah.v, bl, acc[nt], 0, 0, 0);
      acc[nt] = __builtin_amdgcn_mfma_f32_16x16x32_bf16(al.v, bh, acc[nt], 0, 0, 0);
    }
  }
  // D: col = nt*16 + (lane&15), row = kq*4 + r  [measured m89 layout]
#pragma unroll
  for (int r = 0; r < 4; ++r) {
    int row = row0 + kq * 4 + r;
    float dv = dinv[row];
#pragma unroll
    for (int nt = 0; nt < 4; ++nt)
      Hs[((long)row << 6) + nt * 16 + mrow] = (unsigned short)bf16_rne(acc[nt][r] * dv);
  }
}

// ------- gather (packed, 8 edges/group, 4 independent loads): -------
// out[n] = act(dinv[n]*(hs[n]+sum hs[src]) + b). hs32 row = 32 uints (64 bf16).
// Row N_NODES is an all-zero sentinel (covers both lane-tail and group-tail).
template <bool RELU>
__global__ __launch_bounds__(256) void k_gather(const unsigned* __restrict__ hs32,
                                                const int* __restrict__ rowptr,
                                                const int* __restrict__ adj,
                                                const float* __restrict__ dinv,
                                                const float* __restrict__ b,
                                                float* __restrict__ outb) {
  int n = blockIdx.x * 4 + (threadIdx.x >> 6);
  if (n >= N_NODES) return;
  int lane = threadIdx.x & 63;
  int half = lane >> 5;   // which edge of each pair this half-wave handles
  int hl = lane & 31;     // uint index within the 64-feat row
  int s0 = rowptr[n], e0 = rowptr[n + 1];
  float acc0 = 0.f, acc1 = 0.f;
  for (int j = s0; j < e0; j += 64) {
    int cnt = min(64, e0 - j);
    int myadj = (lane < cnt) ? adj[j + lane] : N_NODES;
    int ngrp = (cnt + 7) >> 3;  // groups of 4 pairs = 8 edges
    for (int g = 0; g < ngrp; ++g) {
      int base = 8 * g + half;  // edge idx = 8g + 2u + half, u=0..3
      int a0 = __shfl(myadj, base + 0);
      int a1 = __shfl(myadj, base + 2);
      int a2 = __shfl(myadj, base + 4);
      int a3 = __shfl(myadj, base + 6);
      unsigned u0 = hs32[((unsigned)a0 << 5) + hl];
      unsigned u1 = hs32[((unsigned)a1 << 5) + hl];
      unsigned u2 = hs32[((unsigned)a2 << 5) + hl];
      unsigned u3 = hs32[((unsigned)a3 << 5) + hl];
      union { unsigned u; float f; } t0, t1;
      t0.u = u0 << 16;          acc0 += t0.f;
      t1.u = u0 & 0xffff0000u;  acc1 += t1.f;
      t0.u = u1 << 16;          acc0 += t0.f;
      t1.u = u1 & 0xffff0000u;  acc1 += t1.f;
      t0.u = u2 << 16;          acc0 += t0.f;
      t1.u = u2 & 0xffff0000u;  acc1 += t1.f;
      t0.u = u3 << 16;          acc0 += t0.f;
      t1.u = u3 & 0xffff0000u;  acc1 += t1.f;
    }
  }
  // combine the two half-wave partial sums
  acc0 += __shfl_xor(acc0, 32);
  acc1 += __shfl_xor(acc1, 32);
  // self loop
  unsigned us = hs32[((unsigned)n << 5) + hl];
  union { unsigned u; float f; } slo, shi;
  slo.u = us << 16;
  shi.u = us & 0xffff0000u;
  acc0 += slo.f;
  acc1 += shi.f;
  float dv = dinv[n];
  float2 bb = *(const float2*)&b[2 * hl];
  float v0 = dv * acc0 + bb.x;
  float v1 = dv * acc1 + bb.y;
  if (RELU) { v0 = fmaxf(v0, 0.f); v1 = fmaxf(v1, 0.f); }
  if (half == 0)
    *(float2*)&outb[((long)n << 6) + 2 * hl] = make_float2(v0, v1);
}

// ---------------- pooling: mean + max per sorted-batch segment ----------------
__global__ __launch_bounds__(256) void k_pool(const float* __restrict__ Hf,
                                              const int* __restrict__ batch,
                                              float* __restrict__ pooled) {
  int g = blockIdx.x;
  int start, end;
  {
    int lo = 0, hi = N_NODES;
    while (lo < hi) { int mid = (lo + hi) >> 1; if (batch[mid] < g) lo = mid + 1; else hi = mid; }
    start = lo;
    lo = start; hi = N_NODES;
    while (lo < hi) { int mid = (lo + hi) >> 1; if (batch[mid] < g + 1) lo = mid + 1; else hi = mid; }
    end = lo;
  }
  int lane = threadIdx.x & 63, wave = threadIdx.x >> 6;
  float sum = 0.f, mx = -INFINITY;
  for (int n = start + wave; n < end; n += 4) {
    float v = Hf[((long)n << 6) + lane];
    sum += v;
    mx = fmaxf(mx, v);
  }
  __shared__ float ssum[4][HID];
  __shared__ float smax[4][HID];
  ssum[wave][lane] = sum;
  smax[wave][lane] = mx;
  __syncthreads();
  if (wave == 0) {
    sum = ssum[0][lane] + ssum[1][lane] + ssum[2][lane] + ssum[3][lane];
    mx = fmaxf(fmaxf(smax[0][lane], smax[1][lane]), fmaxf(smax[2][lane], smax[3][lane]));
    int cnt = end - start;
    float mean;
    if (cnt == 0) { mean = 0.f; mx = 0.f; }
    else mean = sum / (float)cnt;
    pooled[g * 2 * HID + lane] = mean;
    pooled[g * 2 * HID + HID + lane] = mx;
  }
}

// ---------------- MLP head ----------------
__global__ __launch_bounds__(64) void k_head(const float* __restrict__ pooled,
                                             const float* __restrict__ fcW1,
                                             const float* __restrict__ fcb1,
                                             const float* __restrict__ fcW2,
                                             const float* __restrict__ fcb2,
                                             float* __restrict__ out) {
  int g = blockIdx.x;
  int lane = threadIdx.x;  // 64
  __shared__ float p[2 * HID];
  p[lane] = pooled[g * 2 * HID + lane];
  p[HID + lane] = pooled[g * 2 * HID + HID + lane];
  __syncthreads();
  float acc = fcb1[lane];
#pragma unroll
  for (int k = 0; k < 2 * HID; ++k) acc += p[k] * fcW1[k * HID + lane];
  acc = fmaxf(acc, 0.f);
  float contrib = acc * fcW2[lane];
#pragma unroll
  for (int off = 32; off > 0; off >>= 1) contrib += __shfl_down(contrib, off);
  if (lane == 0) out[g] = contrib + fcb2[0];
}

extern "C" void kernel_launch(void* const* d_in, const int* in_sizes, int n_in,
                              void* d_out, int out_size, void* d_ws, size_t ws_size,
                              hipStream_t stream) {
  const float* x    = (const float*)d_in[0];
  const int*   ei   = (const int*)d_in[1];
  const int*   bat  = (const int*)d_in[2];
  const float* W1   = (const float*)d_in[3];
  const float* b1   = (const float*)d_in[4];
  const float* W2   = (const float*)d_in[5];
  const float* b2   = (const float*)d_in[6];
  const float* fcW1 = (const float*)d_in[7];
  const float* fcb1 = (const float*)d_in[8];
  const float* fcW2 = (const float*)d_in[9];
  const float* fcb2 = (const float*)d_in[10];
  float* out = (float*)d_out;

  char* ws = (char*)d_ws;
  size_t off = 0;
  auto align = [&]() { off = (off + 127) & ~127ul; };
  int*   bhist  = (int*)(ws + off);   off += NB * 4;            align();
  int*   bbase  = (int*)(ws + off);   off += (NB + 1) * 4;      align();
  int*   bcur   = (int*)(ws + off);   off += NB * 4;            align();
  int*   rowptr = (int*)(ws + off);   off += (N_NODES + 1) * 4; align();
  float* dinv   = (float*)(ws + off); off += N_NODES * 4;       align();
  float* pooled = (float*)(ws + off); off += N_GRAPH * 2 * HID * 4; align();
  int*   adj    = (int*)(ws + off);   off += (size_t)N_EDGES * 4;   align();
  unsigned short* hs = (unsigned short*)(ws + off);
  off += ((size_t)N_NODES + 1) * HID * 2;  // +1 zero sentinel row
  align();
  float* ob     = (float*)(ws + off); off += (size_t)N_NODES * HID * 4;
  int*   pairs  = (int*)ob;  // alias: pairs dead before first write of ob

  // zero the sentinel row (ws is poisoned 0xAA before every call)
  hipMemsetAsync(hs + (size_t)N_NODES * HID, 0, HID * 2, stream);

  // ---- CSR build (shared by both layers) + dinv ----
  hipMemsetAsync(bhist, 0, NB * sizeof(int), stream);
  k_hist<<<400, 256, 0, stream>>>(ei + N_EDGES, bhist);
  k_scanB<<<1, 256, 0, stream>>>(bhist, bbase, bcur);
  k_place<<<(N_EDGES + CHUNK - 1) / CHUNK, 256, 0, stream>>>(ei, bcur, pairs);
  k_build<<<NB, 256, 0, stream>>>(pairs, bbase, rowptr, adj, dinv);

  // ---- layer 1: hs1 = bf16((x@W1)*dinv) ; ob = relu(dinv*(hs1 + gather) + b1) ----
  k_gemm_mfma<DIN><<<(N_NODES + 63) / 64, 256, 0, stream>>>(x, W1, dinv, hs);
  k_gather<true><<<(N_NODES + 3) / 4, 256, 0, stream>>>((const unsigned*)hs, rowptr, adj, dinv, b1, ob);

  // ---- layer 2: hs2 = bf16((ob@W2)*dinv) ; ob = dinv*(hs2 + gather) + b2 ----
  k_gemm_mfma<HID><<<(N_NODES + 63) / 64, 256, 0, stream>>>(ob, W2, dinv, hs);
  k_gather<false><<<(N_NODES + 3) / 4, 256, 0, stream>>>((const unsigned*)hs, rowptr, adj, dinv, b2, ob);

  // ---- pooling + head ----
  k_pool<<<N_GRAPH, 256, 0, stream>>>(ob, bat, pooled);
  k_head<<<N_GRAPH, 64, 0, stream>>>(pooled, fcW1, fcb1, fcW2, fcb2, out);
}